// Round 2
// baseline (136.079 us; speedup 1.0000x reference)
//
#include <hip/hip_runtime.h>

// SimulatedMaxPool3D: 2x2 stride-2 max over (h,w) of (1,32,64,256,256) f32.
// Output 0: (1,32,64,128,128) f32 = 33,554,432 elems.
// Output 1: scalar h = 256.0f at flat offset 33,554,432.
//
// Memory-bound: 512 MiB read + 128 MiB write (input > 256 MiB L3, true HBM).
// R1 change: perfect per-instruction coalescing. Lane i loads float4 at
// byte 16*i -> one wave load = 1 KiB contiguous (a full input row).
// Horizontal 2x2 pairs are inside the float4, so zero cross-lane traffic;
// each thread emits a float2 (wave store = 512 B contiguous).

#define PLANES    2048LL        // n*c*d = 1*32*64
#define IN_HW     65536LL       // 256*256
#define OUT_HW    16384LL       // 128*128
#define UNITS_PER_PLANE 8192    // 128 out rows * 64 float4-column-groups
#define N_UNITS   (PLANES * UNITS_PER_PLANE)   // 16,777,216
#define OUT_ELEMS 33554432LL

__global__ __launch_bounds__(256) void maxpool2x2_kernel(
    const float* __restrict__ x, float* __restrict__ out) {
    const long long stride = (long long)gridDim.x * blockDim.x;
    for (long long tid = (long long)blockIdx.x * blockDim.x + threadIdx.x;
         tid < N_UNITS; tid += stride) {
        const long long plane = tid >> 13;          // /8192
        const int rem = (int)(tid & 8191);
        const int oh = rem >> 6;                    // output row 0..127
        const int og = rem & 63;                    // float4 column group 0..63

        const float* base = x + plane * IN_HW + (long long)(oh * 2) * 256 + og * 4;
        const float4 a = *reinterpret_cast<const float4*>(base);        // row 2*oh
        const float4 b = *reinterpret_cast<const float4*>(base + 256);  // row 2*oh+1

        float2 r;
        r.x = fmaxf(fmaxf(a.x, a.y), fmaxf(b.x, b.y));
        r.y = fmaxf(fmaxf(a.z, a.w), fmaxf(b.z, b.w));

        *reinterpret_cast<float2*>(out + plane * OUT_HW + (long long)oh * 128 + og * 2) = r;
    }
    if (blockIdx.x == 0 && threadIdx.x == 0) {
        out[OUT_ELEMS] = 256.0f;   // second tuple output: h = x.shape[3]
    }
}

extern "C" void kernel_launch(void* const* d_in, const int* in_sizes, int n_in,
                              void* d_out, int out_size, void* d_ws, size_t ws_size,
                              hipStream_t stream) {
    const float* x = (const float*)d_in[0];
    float* out = (float*)d_out;
    // Memory-bound: cap grid at 2048 blocks (8 blocks/CU), grid-stride the rest.
    maxpool2x2_kernel<<<2048, 256, 0, stream>>>(x, out);
}

// Round 4
// 110.992 us; speedup vs baseline: 1.2260x; 1.2260x over previous
//
#include <hip/hip_runtime.h>

// SimulatedMaxPool3D: 2x2 stride-2 max over (h,w) of (1,32,64,256,256) f32.
// Output 0: (1,32,64,128,128) f32 = 33,554,432 elems.
// Output 1: scalar h = 256.0f at flat offset 33,554,432.
//
// R3 = R2 with clang ext_vector_type instead of HIP_vector_type so the
// nontemporal builtins compile. Exact-map 2D grid, no grid-stride loop:
// each thread does 2 float4-NT loads + 1 float2-NT store, fire-and-forget.

typedef float f32x4 __attribute__((ext_vector_type(4)));
typedef float f32x2 __attribute__((ext_vector_type(2)));

#define IN_HW     65536u        // 256*256
#define OUT_HW    16384u        // 128*128
#define OUT_ELEMS 33554432u

__global__ __launch_bounds__(256) void maxpool2x2_kernel(
    const float* __restrict__ x, float* __restrict__ out) {
    const unsigned plane = blockIdx.y;                       // 0..2047 (c*d)
    const unsigned unit  = blockIdx.x * 256u + threadIdx.x;  // 0..8191
    const unsigned oh = unit >> 6;                           // output row 0..127
    const unsigned og = unit & 63u;                          // float4 col group 0..63

    const float* base = x + (size_t)plane * IN_HW + (oh * 2u) * 256u + og * 4u;
    const f32x4 a = __builtin_nontemporal_load(reinterpret_cast<const f32x4*>(base));
    const f32x4 b = __builtin_nontemporal_load(reinterpret_cast<const f32x4*>(base + 256));

    f32x2 r;
    r.x = fmaxf(fmaxf(a.x, a.y), fmaxf(b.x, b.y));
    r.y = fmaxf(fmaxf(a.z, a.w), fmaxf(b.z, b.w));

    __builtin_nontemporal_store(
        r, reinterpret_cast<f32x2*>(out + (size_t)plane * OUT_HW + oh * 128u + og * 2u));

    if (plane == 0u && unit == 0u) {
        out[OUT_ELEMS] = 256.0f;   // second tuple output: h = x.shape[3]
    }
}

extern "C" void kernel_launch(void* const* d_in, const int* in_sizes, int n_in,
                              void* d_out, int out_size, void* d_ws, size_t ws_size,
                              hipStream_t stream) {
    const float* x = (const float*)d_in[0];
    float* out = (float*)d_out;
    // Exact map: 32 blocks per plane (8192 threads) x 2048 planes.
    dim3 grid(32, 2048, 1);
    maxpool2x2_kernel<<<grid, 256, 0, stream>>>(x, out);
}